// Round 5
// baseline (153.600 us; speedup 1.0000x reference)
//
#include <hip/hip_runtime.h>
#include <hip/hip_bf16.h>
#include <stdint.h>

#define EPSBN 1e-5f

typedef float f32x4 __attribute__((ext_vector_type(4)));
typedef __bf16 bf16x8 __attribute__((ext_vector_type(8)));

#define BB 8
#define XCH 1024
#define YCH 512
#define CCH 512
#define PP  4096   // H*W = 64*64

__device__ __forceinline__ unsigned short f2bf(float f) {
    union { float f; uint32_t u; } v; v.f = f;
    uint32_t r = v.u + 0x7fffu + ((v.u >> 16) & 1u);   // RNE
    return (unsigned short)(r >> 16);
}

__device__ __forceinline__ void gload16(const void* g, void* l) {
    __builtin_amdgcn_global_load_lds(
        (__attribute__((address_space(1))) void*)(g),
        (__attribute__((address_space(3))) void*)(l),
        16, 0, 0);
}

// ---------- fused: y_pool (blocks 0..4095) + weight cvt (blocks 4096..4863) ----------
__global__ __launch_bounds__(256)
void k_pre(const float* __restrict__ y, const float* __restrict__ wred, const float* __restrict__ wfus,
           float* __restrict__ ypool, unsigned short* __restrict__ wred_bf, unsigned short* __restrict__ wfus_bf) {
    int bx = blockIdx.x, t = threadIdx.x;
    if (bx < 4096) {
        const float4* base = (const float4*)(y + (size_t)bx * PP);
        float s = 0.f;
#pragma unroll
        for (int it = 0; it < 4; ++it) {
            float4 v = base[t + it * 256];
            s += v.x + v.y + v.z + v.w;
        }
#pragma unroll
        for (int off = 32; off > 0; off >>= 1) s += __shfl_down(s, off);
        __shared__ float wsum[4];
        if ((t & 63) == 0) wsum[t >> 6] = s;
        __syncthreads();
        if (t == 0) ypool[bx] = (wsum[0] + wsum[1] + wsum[2] + wsum[3]) * (1.f / 4096.f);
    } else {
        int idx = (bx - 4096) * 256 + t;                   // < 196608
        const int n1 = CCH * XCH / 4;                      // 131072
        float4 v; unsigned short* dst;
        if (idx < n1) { v = ((const float4*)wred)[idx]; dst = wred_bf + (size_t)idx * 4; }
        else { int j = idx - n1; v = ((const float4*)wfus)[j]; dst = wfus_bf + (size_t)j * 4; }
        uint32_t lo = (uint32_t)f2bf(v.x) | ((uint32_t)f2bf(v.y) << 16);
        uint32_t hi = (uint32_t)f2bf(v.z) | ((uint32_t)f2bf(v.w) << 16);
        *(uint2*)dst = make_uint2(lo, hi);
    }
}

// ---------- fused: G (blocks 0..15) + BN-const folding (blocks 16..17) ----------
__global__ __launch_bounds__(256)
void k_gf2(const float* __restrict__ wgen, const float* __restrict__ bgen,
           const float* __restrict__ ggen, const float* __restrict__ begen,
           const float* __restrict__ mgen, const float* __restrict__ vgen,
           const float* __restrict__ ypool,
           const float* g_red, const float* be_red, const float* m_red, const float* v_red, const float* b_red,
           const float* g_act, const float* be_act, const float* m_act, const float* v_act,
           const float* g_fus, const float* be_fus, const float* m_fus, const float* v_fus, const float* b_fus,
           float* __restrict__ G, float* A1, float* B1, float* CACT, float* A2, float* B2) {
    int bx = blockIdx.x, t = threadIdx.x;
    if (bx < 16) {
        int idx = bx * 256 + t;
        int b = idx >> 9, c = idx & 511;
        const float4* wr = (const float4*)(wgen + (size_t)c * YCH);
        const float4* yp = (const float4*)(ypool + b * YCH);
        float dot = 0.f;
        for (int k = 0; k < YCH / 4; ++k) {
            float4 w = wr[k], v = yp[k];
            dot += w.x * v.x + w.y * v.y + w.z * v.z + w.w * v.w;
        }
        float ag = ggen[c] * rsqrtf(vgen[c] + EPSBN);
        float gf = fmaxf(ag * (dot + bgen[c] - mgen[c]) + begen[c], 0.f);
        float aa = g_act[c] * rsqrtf(v_act[c] + EPSBN);
        G[idx] = aa * gf;
    } else {
        int c = (bx - 16) * 256 + t;
        if (c >= CCH) return;
        float a1 = g_red[c] * rsqrtf(v_red[c] + EPSBN);
        A1[c] = a1;
        B1[c] = a1 * (b_red[c] - m_red[c]) + be_red[c];
        float aa = g_act[c] * rsqrtf(v_act[c] + EPSBN);
        CACT[c] = be_act[c] - aa * m_act[c];
        float a2 = g_fus[c] * rsqrtf(v_fus[c] + EPSBN);
        A2[c] = a2;
        B2[c] = a2 * (b_fus[c] - m_fus[c]) + be_fus[c];
    }
}

// ============================================================================
// GEMM1: h[b][p][c] = epi( sum_k x[b][k][p] * wred[c][k] )
// 128x128 tile, BK=32, 4 waves, 32KB LDS, double-buffered, 1 barrier/tile.
// LDS unit u = row*4 + kgrp; swizzle punit = u ^ ((u>>4)&7) (involution):
//   - frag ds_read_b128: uniform bank spread (conflict-free)
//   - A transpose ds_write_b64: 8 distinct bank-quads per quarter-wave
//   - B gload16: linear dest, source pre-XOR'd with the same involution
// A-side: fp32 x [k][p] reg-staged (4 coalesced float4/thread) -> in-reg
//   4x4 transpose+cvt -> 4 ds_write_b64 into the swizzled [p][k] layout.
// ============================================================================
__global__ __launch_bounds__(256, 3)
void k_gemm1(const float* __restrict__ X, const unsigned short* __restrict__ Bt,
             unsigned short* __restrict__ H,
             const float* __restrict__ C0, const float* __restrict__ C1,
             const float* __restrict__ C2, const float* __restrict__ G) {
    __shared__ __align__(16) char sm[32768];
    constexpr int NT = 32;      // K=1024 / BK=32

    // grid (4 n, 32 m, 8 b) -> batch-per-XCD chunking (1024 % 8 == 0, bijective)
    int r = blockIdx.x + (blockIdx.y << 2) + (blockIdx.z << 7);
    int w = ((r & 7) << 7) | (r >> 3);
    const int n0 = (w & 3) << 7;
    const int m0 = ((w >> 2) & 31) << 7;
    const int bz = w >> 7;

    const int t = threadIdx.x;
    const int lane = t & 63, wave = t >> 6;
    const int l15 = lane & 15, l4v = lane >> 4;
    const int wm = wave >> 1, wn = wave & 1;

    // ---- B staging (2 gload16/tile): linear LDS dest, inverse-swizzled source
    int dU0 = (wave << 6) + lane;
    int dU1 = 256 + dU0;
    int sU0 = dU0 ^ ((dU0 >> 4) & 7);
    int sU1 = dU1 ^ ((dU1 >> 4) & 7);
    const unsigned short* Bbase = Bt + (size_t)n0 * 1024;
    const unsigned short* pB0 = Bbase + (sU0 >> 2) * 1024 + (sU0 & 3) * 8;
    const unsigned short* pB1 = Bbase + (sU1 >> 2) * 1024 + (sU1 & 3) * 8;
    char* const stB = sm + 16384 + (wave << 10);

#define STAGE_B(tt) { int nb_ = (((tt) & 1) << 13); \
        gload16(pB0 + (tt) * 32, stB + nb_); \
        gload16(pB1 + (tt) * 32, stB + nb_ + 4096); }

    // ---- A staging: pq = lane&31 (p-quad), kq = wave*2 + lane>>5 (k-quad)
    const int pq = lane & 31;
    const int kq = (wave << 1) + (lane >> 5);
    const float* xbase = X + (size_t)bz * ((size_t)XCH * PP) + m0 + (pq << 2);
    float4 a0, a1, a2, a3;

#define ALOAD(tt) { const float* px_ = xbase + (size_t)((tt) * 32 + (kq << 2)) * PP; \
        a0 = *(const float4*)px_;            a1 = *(const float4*)(px_ + PP); \
        a2 = *(const float4*)(px_ + 2 * PP); a3 = *(const float4*)(px_ + 3 * PP); }

#define AWRITE(tt) { char* ab_ = sm + (((tt) & 1) << 13); \
        _Pragma("unroll") \
        for (int rr = 0; rr < 4; ++rr) { \
            int row_ = (pq << 2) + rr; \
            int u_ = (row_ << 2) + (kq >> 1); \
            int byt_ = ((u_ ^ ((u_ >> 4) & 7)) << 4) + ((kq & 1) << 3); \
            uint32_t lo_ = (uint32_t)f2bf(((const float*)&a0)[rr]) | ((uint32_t)f2bf(((const float*)&a1)[rr]) << 16); \
            uint32_t hi_ = (uint32_t)f2bf(((const float*)&a2)[rr]) | ((uint32_t)f2bf(((const float*)&a3)[rr]) << 16); \
            *(uint2*)(ab_ + byt_) = make_uint2(lo_, hi_); } }

    f32x4 acc[4][4];
#pragma unroll
    for (int i = 0; i < 4; ++i)
#pragma unroll
        for (int j = 0; j < 4; ++j) acc[i][j] = (f32x4){0.f, 0.f, 0.f, 0.f};

    // ---- prologue: tile 0 ----
    ALOAD(0)
    STAGE_B(0)
    AWRITE(0)
    __syncthreads();

    for (int tk = 0; tk < NT; ++tk) {
        const int bo = (tk & 1) << 13;
        bf16x8 af[4], bfr[4];
#pragma unroll
        for (int i = 0; i < 4; ++i) {
            int u = ((((wm << 6) + (i << 4) + l15) << 2) | l4v);
            af[i] = *(const bf16x8*)(sm + bo + ((u ^ ((u >> 4) & 7)) << 4));
        }
#pragma unroll
        for (int j = 0; j < 4; ++j) {
            int u = ((((wn << 6) + (j << 4) + l15) << 2) | l4v);
            bfr[j] = *(const bf16x8*)(sm + 16384 + bo + ((u ^ ((u >> 4) & 7)) << 4));
        }
        if (tk + 1 < NT) { ALOAD(tk + 1) STAGE_B(tk + 1) }
#pragma unroll
        for (int i = 0; i < 4; ++i)
#pragma unroll
            for (int j = 0; j < 4; ++j)
                acc[i][j] = __builtin_amdgcn_mfma_f32_16x16x32_bf16(af[i], bfr[j], acc[i][j], 0, 0, 0);
        if (tk + 1 < NT) { AWRITE(tk + 1) }
        __syncthreads();
    }
#undef STAGE_B
#undef ALOAD
#undef AWRITE

    // ---- epilogue: relu(bn_red) * G + CACT, relu -> bf16 h[p][c] ----
    unsigned short* Ob = H + (size_t)bz * ((size_t)PP * CCH);
    const float* Gb = G + (size_t)bz * CCH;
#pragma unroll
    for (int j = 0; j < 4; ++j) {
        int c = n0 + (wn << 6) + (j << 4) + l15;
        float a1c = C0[c], b1c = C1[c], cac = C2[c], gc = Gb[c];
#pragma unroll
        for (int i = 0; i < 4; ++i) {
            int pr = m0 + (wm << 6) + (i << 4) + (l4v << 2);
#pragma unroll
            for (int q = 0; q < 4; ++q) {
                float xr = fmaxf(a1c * acc[i][j][q] + b1c, 0.f);
                float hv = fmaxf(gc * xr + cac, 0.f);
                Ob[(size_t)(pr + q) * CCH + c] = f2bf(hv);
            }
        }
    }
}

// ============================================================================
// GEMM2: out[b][c][p] = relu(bn_fus(wfus . h)), A = wfus_bf [c][k], B = h [p][k]
// Same 128x128/BK32/4-wave/1-barrier skeleton; both operands via gload16.
// ============================================================================
__global__ __launch_bounds__(256, 3)
void k_gemm2(const unsigned short* __restrict__ A, const unsigned short* __restrict__ Bt,
             float* __restrict__ Out,
             const float* __restrict__ C0, const float* __restrict__ C1) {
    __shared__ __align__(16) char sm[32768];
    constexpr int NT = 16;      // K=512 / BK=32

    // grid (32 n, 4 m, 8 b) -> batch-per-XCD chunking
    int r = blockIdx.x + (blockIdx.y << 5) + (blockIdx.z << 7);
    int w = ((r & 7) << 7) | (r >> 3);
    const int n0 = (w & 31) << 7;        // p
    const int m0 = ((w >> 5) & 3) << 7;  // c
    const int bz = w >> 7;

    const int t = threadIdx.x;
    const int lane = t & 63, wave = t >> 6;
    const int l15 = lane & 15, l4v = lane >> 4;
    const int wm = wave >> 1, wn = wave & 1;

    int dU0 = (wave << 6) + lane;
    int dU1 = 256 + dU0;
    int sU0 = dU0 ^ ((dU0 >> 4) & 7);
    int sU1 = dU1 ^ ((dU1 >> 4) & 7);
    const unsigned short* Abase = A + (size_t)m0 * 512;
    const unsigned short* pA0 = Abase + (sU0 >> 2) * 512 + (sU0 & 3) * 8;
    const unsigned short* pA1 = Abase + (sU1 >> 2) * 512 + (sU1 & 3) * 8;
    const unsigned short* Bbase = Bt + (size_t)bz * ((size_t)PP * CCH) + (size_t)n0 * 512;
    const unsigned short* pB0 = Bbase + (sU0 >> 2) * 512 + (sU0 & 3) * 8;
    const unsigned short* pB1 = Bbase + (sU1 >> 2) * 512 + (sU1 & 3) * 8;
    char* const stA = sm + (wave << 10);
    char* const stB = sm + 16384 + (wave << 10);

#define STAGE2(tt) { int nb_ = (((tt) & 1) << 13); \
        gload16(pA0 + (tt) * 32, stA + nb_); \
        gload16(pA1 + (tt) * 32, stA + nb_ + 4096); \
        gload16(pB0 + (tt) * 32, stB + nb_); \
        gload16(pB1 + (tt) * 32, stB + nb_ + 4096); }

    f32x4 acc[4][4];
#pragma unroll
    for (int i = 0; i < 4; ++i)
#pragma unroll
        for (int j = 0; j < 4; ++j) acc[i][j] = (f32x4){0.f, 0.f, 0.f, 0.f};

    STAGE2(0)
    __syncthreads();

    for (int tk = 0; tk < NT; ++tk) {
        const int bo = (tk & 1) << 13;
        bf16x8 af[4], bfr[4];
#pragma unroll
        for (int i = 0; i < 4; ++i) {
            int u = ((((wm << 6) + (i << 4) + l15) << 2) | l4v);
            af[i] = *(const bf16x8*)(sm + bo + ((u ^ ((u >> 4) & 7)) << 4));
        }
#pragma unroll
        for (int j = 0; j < 4; ++j) {
            int u = ((((wn << 6) + (j << 4) + l15) << 2) | l4v);
            bfr[j] = *(const bf16x8*)(sm + 16384 + bo + ((u ^ ((u >> 4) & 7)) << 4));
        }
        if (tk + 1 < NT) { STAGE2(tk + 1) }
#pragma unroll
        for (int i = 0; i < 4; ++i)
#pragma unroll
            for (int j = 0; j < 4; ++j)
                acc[i][j] = __builtin_amdgcn_mfma_f32_16x16x32_bf16(af[i], bfr[j], acc[i][j], 0, 0, 0);
        __syncthreads();
    }
#undef STAGE2

    // epilogue: fp32 out, BN_fus + ReLU; out[b][c][p]
    float* Ob = Out + (size_t)bz * ((size_t)CCH * PP);
#pragma unroll
    for (int i = 0; i < 4; ++i) {
#pragma unroll
        for (int q = 0; q < 4; ++q) {
            int orow = m0 + (wm << 6) + (i << 4) + (l4v << 2) + q;
            float a2 = C0[orow], b2 = C1[orow];
#pragma unroll
            for (int j = 0; j < 4; ++j) {
                int pc = n0 + (wn << 6) + (j << 4) + l15;
                Ob[(size_t)orow * PP + pc] = fmaxf(a2 * acc[i][j][q] + b2, 0.f);
            }
        }
    }
}

extern "C" void kernel_launch(void* const* d_in, const int* in_sizes, int n_in,
                              void* d_out, int out_size, void* d_ws, size_t ws_size,
                              hipStream_t stream) {
    const float* x      = (const float*)d_in[0];
    const float* y      = (const float*)d_in[1];
    const float* w_red  = (const float*)d_in[2];
    const float* b_red  = (const float*)d_in[3];
    const float* g_red  = (const float*)d_in[4];
    const float* be_red = (const float*)d_in[5];
    const float* m_red  = (const float*)d_in[6];
    const float* v_red  = (const float*)d_in[7];
    const float* w_gen  = (const float*)d_in[8];
    const float* b_gen  = (const float*)d_in[9];
    const float* g_gen  = (const float*)d_in[10];
    const float* be_gen = (const float*)d_in[11];
    const float* m_gen  = (const float*)d_in[12];
    const float* v_gen  = (const float*)d_in[13];
    const float* g_act  = (const float*)d_in[14];
    const float* be_act = (const float*)d_in[15];
    const float* m_act  = (const float*)d_in[16];
    const float* v_act  = (const float*)d_in[17];
    const float* w_fus  = (const float*)d_in[18];
    const float* b_fus  = (const float*)d_in[19];
    const float* g_fus  = (const float*)d_in[20];
    const float* be_fus = (const float*)d_in[21];
    const float* m_fus  = (const float*)d_in[22];
    const float* v_fus  = (const float*)d_in[23];

    // workspace layout (bytes)
    const size_t off_h    = 67108864;                   // 33554432
    const size_t off_wred = 100663296;                  // 1048576
    const size_t off_wfus = 101711872;                  // 524288
    const size_t off_pool = 102236160;                  // 16384
    const size_t off_G    = 102252544;                  // 16384
    const size_t off_cst  = 102268928;                  // 6*2048
    const size_t need     = off_cst + 6 * 2048;
    if (ws_size < need) return;

    char* ws = (char*)d_ws;
    unsigned short* h       = (unsigned short*)(ws + off_h);
    unsigned short* wred_bf = (unsigned short*)(ws + off_wred);
    unsigned short* wfus_bf = (unsigned short*)(ws + off_wfus);
    float* ypool = (float*)(ws + off_pool);
    float* G     = (float*)(ws + off_G);
    float* A1    = (float*)(ws + off_cst);
    float* B1    = A1 + 512;
    float* CACT  = B1 + 512;
    float* A2    = CACT + 512;
    float* B2    = A2 + 512;

    k_pre<<<4864, 256, 0, stream>>>(y, w_red, w_fus, ypool, wred_bf, wfus_bf);
    k_gf2<<<18, 256, 0, stream>>>(w_gen, b_gen, g_gen, be_gen, m_gen, v_gen, ypool,
                                  g_red, be_red, m_red, v_red, b_red,
                                  g_act, be_act, m_act, v_act,
                                  g_fus, be_fus, m_fus, v_fus, b_fus,
                                  G, A1, B1, CACT, A2, B2);

    dim3 g1(4, 32, 8);   // n=512/128, m=4096/128, batch
    k_gemm1<<<g1, 256, 0, stream>>>(x, wred_bf, h, A1, B1, CACT, G);
    dim3 g2(32, 4, 8);   // n=4096/128, m=512/128, batch
    k_gemm2<<<g2, 256, 0, stream>>>(wfus_bf, h, (float*)d_out, A2, B2);
}

// Round 6
// 129.601 us; speedup vs baseline: 1.1852x; 1.1852x over previous
//
#include <hip/hip_runtime.h>
#include <hip/hip_bf16.h>
#include <stdint.h>

#define EPSBN 1e-5f

typedef float f32x4 __attribute__((ext_vector_type(4)));
typedef __bf16 bf16x8 __attribute__((ext_vector_type(8)));

#define BB 8
#define XCH 1024
#define YCH 512
#define CCH 512
#define PP  4096   // H*W = 64*64

__device__ __forceinline__ unsigned short f2bf(float f) {
    union { float f; uint32_t u; } v; v.f = f;
    uint32_t r = v.u + 0x7fffu + ((v.u >> 16) & 1u);   // RNE
    return (unsigned short)(r >> 16);
}

__device__ __forceinline__ uint32_t pkbf(float lo, float hi) {
    uint32_t r;
    asm volatile("v_cvt_pk_bf16_f32 %0, %1, %2" : "=v"(r) : "v"(lo), "v"(hi));
    return r;
}

__device__ __forceinline__ void gload16(const void* g, void* l) {
    __builtin_amdgcn_global_load_lds(
        (__attribute__((address_space(1))) void*)(g),
        (__attribute__((address_space(3))) void*)(l),
        16, 0, 0);
}

// ---------- fused: y_pool (blocks 0..4095) + weight cvt (blocks 4096..4863) ----------
__global__ __launch_bounds__(256)
void k_pre(const float* __restrict__ y, const float* __restrict__ wred, const float* __restrict__ wfus,
           float* __restrict__ ypool, unsigned short* __restrict__ wred_bf, unsigned short* __restrict__ wfus_bf) {
    int bx = blockIdx.x, t = threadIdx.x;
    if (bx < 4096) {
        const float4* base = (const float4*)(y + (size_t)bx * PP);
        float s = 0.f;
#pragma unroll
        for (int it = 0; it < 4; ++it) {
            float4 v = base[t + it * 256];
            s += v.x + v.y + v.z + v.w;
        }
#pragma unroll
        for (int off = 32; off > 0; off >>= 1) s += __shfl_down(s, off);
        __shared__ float wsum[4];
        if ((t & 63) == 0) wsum[t >> 6] = s;
        __syncthreads();
        if (t == 0) ypool[bx] = (wsum[0] + wsum[1] + wsum[2] + wsum[3]) * (1.f / 4096.f);
    } else {
        int idx = (bx - 4096) * 256 + t;                   // < 196608
        const int n1 = CCH * XCH / 4;                      // 131072
        float4 v; unsigned short* dst;
        if (idx < n1) { v = ((const float4*)wred)[idx]; dst = wred_bf + (size_t)idx * 4; }
        else { int j = idx - n1; v = ((const float4*)wfus)[j]; dst = wfus_bf + (size_t)j * 4; }
        *(uint2*)dst = make_uint2(((uint32_t)f2bf(v.x)) | ((uint32_t)f2bf(v.y) << 16),
                                  ((uint32_t)f2bf(v.z)) | ((uint32_t)f2bf(v.w) << 16));
    }
}

// ---------- fused: G (blocks 0..15) + BN-const folding (blocks 16..17) ----------
__global__ __launch_bounds__(256)
void k_gf2(const float* __restrict__ wgen, const float* __restrict__ bgen,
           const float* __restrict__ ggen, const float* __restrict__ begen,
           const float* __restrict__ mgen, const float* __restrict__ vgen,
           const float* __restrict__ ypool,
           const float* g_red, const float* be_red, const float* m_red, const float* v_red, const float* b_red,
           const float* g_act, const float* be_act, const float* m_act, const float* v_act,
           const float* g_fus, const float* be_fus, const float* m_fus, const float* v_fus, const float* b_fus,
           float* __restrict__ G, float* A1, float* B1, float* CACT, float* A2, float* B2) {
    int bx = blockIdx.x, t = threadIdx.x;
    if (bx < 16) {
        int idx = bx * 256 + t;
        int b = idx >> 9, c = idx & 511;
        const float4* wr = (const float4*)(wgen + (size_t)c * YCH);
        const float4* yp = (const float4*)(ypool + b * YCH);
        float dot = 0.f;
        for (int k = 0; k < YCH / 4; ++k) {
            float4 w = wr[k], v = yp[k];
            dot += w.x * v.x + w.y * v.y + w.z * v.z + w.w * v.w;
        }
        float ag = ggen[c] * rsqrtf(vgen[c] + EPSBN);
        float gf = fmaxf(ag * (dot + bgen[c] - mgen[c]) + begen[c], 0.f);
        float aa = g_act[c] * rsqrtf(v_act[c] + EPSBN);
        G[idx] = aa * gf;
    } else {
        int c = (bx - 16) * 256 + t;
        if (c >= CCH) return;
        float a1 = g_red[c] * rsqrtf(v_red[c] + EPSBN);
        A1[c] = a1;
        B1[c] = a1 * (b_red[c] - m_red[c]) + be_red[c];
        float aa = g_act[c] * rsqrtf(v_act[c] + EPSBN);
        CACT[c] = be_act[c] - aa * m_act[c];
        float a2 = g_fus[c] * rsqrtf(v_fus[c] + EPSBN);
        A2[c] = a2;
        B2[c] = a2 * (b_fus[c] - m_fus[c]) + be_fus[c];
    }
}

// ============================================================================
// GEMM1: h[b][p][c] = epi( sum_k x[b][k][p] * wred[c][k] )
// 128x128 tile, BK=64, 4 waves, depth-2 pipeline, 1 raw s_barrier/tile.
// LDS: Abuf 2x16KB @0, Bbuf 3x16KB @32768 (80KB -> 2 blocks/CU).
// Swizzle: unit(row,kg) stored at kg' = kg ^ ((row ^ (row>>2)) & 7).
//   frag reads 2-way (free); transpose ds_write_b128 2-way (free).
// Steady interval t: reads | vmcnt(4) AWRITE(t+1) | ALOAD(t+2) STAGE_B(t+2)
//   | 32 MFMA | vmcnt(12) lgkmcnt(0) | s_barrier.  (waits only touch loads
//   issued >= 1 interval earlier; B(t+1) retired BEFORE the barrier that
//   gates its cross-wave consumption.)
// ============================================================================
__global__ __launch_bounds__(256, 2)
void k_gemm1(const float* __restrict__ X, const unsigned short* __restrict__ Bt,
             unsigned short* __restrict__ H,
             const float* __restrict__ C0, const float* __restrict__ C1,
             const float* __restrict__ C2, const float* __restrict__ G) {
    __shared__ __align__(16) char sm[81920];
    constexpr int NT = 16;      // K=1024 / BK=64

    int r = blockIdx.x + (blockIdx.y << 2) + (blockIdx.z << 7);
    int w = ((r & 7) << 7) | (r >> 3);          // batch-chunk per XCD
    const int n0 = (w & 3) << 7;
    const int m0 = ((w >> 2) & 31) << 7;
    const int bz = w >> 7;

    const int t = threadIdx.x;
    const int lane = t & 63, wave = t >> 6;
    const int l15 = lane & 15, l4v = lane >> 4;
    const int wm = wave >> 1, wn = wave & 1;

    // ---- A-path mapping: pq = p-quad (lane&31), ko = k-octet (0..7)
    const int pq = lane & 31;
    const int ko = (wave << 1) | (lane >> 5);
    const float* xb = X + (size_t)bz * ((size_t)XCH * PP) + m0 + (pq << 2);
    int awb[4];
#pragma unroll
    for (int rr = 0; rr < 4; ++rr) {
        int row = (pq << 2) + rr;
        int mm = (row ^ (row >> 2)) & 7;
        awb[rr] = row * 128 + ((ko ^ mm) << 4);
    }

    // ---- B staging: 4 gload16/tile; dest linear (wave base), source pre-swizzled
    const unsigned short* Bbase = Bt + (size_t)n0 * 1024;
    const unsigned short* pBsrc[4];
    int bdst[4];
#pragma unroll
    for (int q = 0; q < 4; ++q) {
        int du = (wave << 6) + lane + (q << 8);
        int row = du >> 3, g = du & 7;
        int mm = (row ^ (row >> 2)) & 7;
        pBsrc[q] = Bbase + (size_t)row * 1024 + ((g ^ mm) << 3);
        bdst[q] = ((wave << 6) + (q << 8)) << 4;   // wave-uniform; HW adds lane*16
    }

    // ---- frag read byte offsets (loop-invariant)
    int offA[4][2], offB[4][2];
#pragma unroll
    for (int i = 0; i < 4; ++i) {
        int rowA = (wm << 6) + (i << 4) + l15;
        int mA = (rowA ^ (rowA >> 2)) & 7;
        int rowB = (wn << 6) + (i << 4) + l15;
        int mB = (rowB ^ (rowB >> 2)) & 7;
#pragma unroll
        for (int k2 = 0; k2 < 2; ++k2) {
            offA[i][k2] = rowA * 128 + ((((k2 << 2) | l4v) ^ mA) << 4);
            offB[i][k2] = rowB * 128 + ((((k2 << 2) | l4v) ^ mB) << 4);
        }
    }

    float4 R0, R1, R2, R3, R4, R5, R6, R7;
#define ALOAD(tt) { const float* p_ = xb + (size_t)((tt) * 64 + (ko << 3)) * PP; \
        R0 = *(const float4*)p_;              R1 = *(const float4*)(p_ + PP); \
        R2 = *(const float4*)(p_ + 2 * PP);   R3 = *(const float4*)(p_ + 3 * PP); \
        R4 = *(const float4*)(p_ + 4 * PP);   R5 = *(const float4*)(p_ + 5 * PP); \
        R6 = *(const float4*)(p_ + 6 * PP);   R7 = *(const float4*)(p_ + 7 * PP); }

#define AWRITE(buf2) { char* ab_ = sm + ((buf2) << 14); \
        _Pragma("unroll") \
        for (int rr = 0; rr < 4; ++rr) { \
            uint4 v_; \
            v_.x = pkbf(((const float*)&R0)[rr], ((const float*)&R1)[rr]); \
            v_.y = pkbf(((const float*)&R2)[rr], ((const float*)&R3)[rr]); \
            v_.z = pkbf(((const float*)&R4)[rr], ((const float*)&R5)[rr]); \
            v_.w = pkbf(((const float*)&R6)[rr], ((const float*)&R7)[rr]); \
            *(uint4*)(ab_ + awb[rr]) = v_; } }

#define STAGE_B(tt, b3_) { char* d_ = sm + 32768 + ((b3_) << 14); \
        gload16(pBsrc[0] + (tt) * 64, d_ + bdst[0]); \
        gload16(pBsrc[1] + (tt) * 64, d_ + bdst[1]); \
        gload16(pBsrc[2] + (tt) * 64, d_ + bdst[2]); \
        gload16(pBsrc[3] + (tt) * 64, d_ + bdst[3]); }

    f32x4 acc[4][4];
#pragma unroll
    for (int i = 0; i < 4; ++i)
#pragma unroll
        for (int j = 0; j < 4; ++j) acc[i][j] = (f32x4){0.f, 0.f, 0.f, 0.f};

    // ---- prologue ----
    ALOAD(0)
    asm volatile("" ::: "memory");
    STAGE_B(0, 0)
    asm volatile("s_waitcnt vmcnt(4)" ::: "memory");     // A(0) in regs (B(0) still flying)
    AWRITE(0)                                            // -> Abuf[0]
    ALOAD(1)
    asm volatile("" ::: "memory");
    STAGE_B(1, 1)
    asm volatile("s_waitcnt vmcnt(12) lgkmcnt(0)" ::: "memory");  // B(0) landed, AWRITE visible
    __builtin_amdgcn_s_barrier();                        // entering t=0: [A(1)=8, B(1)=4]

    int b3 = 0;
    for (int tk = 0; tk < NT; ++tk) {
        char* aB = sm + ((tk & 1) << 14);
        char* bB = sm + 32768 + (b3 << 14);
        bf16x8 a0[4], b0[4], a1[4], b1[4];
#pragma unroll
        for (int i = 0; i < 4; ++i) {
            a0[i] = *(const bf16x8*)(aB + offA[i][0]);
            b0[i] = *(const bf16x8*)(bB + offB[i][0]);
            a1[i] = *(const bf16x8*)(aB + offA[i][1]);
            b1[i] = *(const bf16x8*)(bB + offB[i][1]);
        }
        if (tk + 1 < NT) {
            asm volatile("s_waitcnt vmcnt(4)" ::: "memory");   // own A(tk+1) regs ready
            AWRITE((tk + 1) & 1)
        }
        if (tk + 2 < NT) {
            int nb = b3 - 1; if (nb < 0) nb += 3;              // (b3+2)%3
            ALOAD(tk + 2)
            asm volatile("" ::: "memory");                     // pin A-before-B issue order
            STAGE_B(tk + 2, nb)
        }
#pragma unroll
        for (int i = 0; i < 4; ++i)
#pragma unroll
            for (int j = 0; j < 4; ++j)
                acc[i][j] = __builtin_amdgcn_mfma_f32_16x16x32_bf16(a0[i], b0[j], acc[i][j], 0, 0, 0);
#pragma unroll
        for (int i = 0; i < 4; ++i)
#pragma unroll
            for (int j = 0; j < 4; ++j)
                acc[i][j] = __builtin_amdgcn_mfma_f32_16x16x32_bf16(a1[i], b1[j], acc[i][j], 0, 0, 0);
        if (tk < NT - 2) {
            asm volatile("s_waitcnt vmcnt(12) lgkmcnt(0)" ::: "memory");  // B(tk+1) landed pre-barrier
            __builtin_amdgcn_s_barrier();
        } else if (tk == NT - 2) {
            asm volatile("s_waitcnt vmcnt(0) lgkmcnt(0)" ::: "memory");
            __builtin_amdgcn_s_barrier();
        }
        b3 = (b3 == 2) ? 0 : b3 + 1;
    }
#undef ALOAD
#undef AWRITE
#undef STAGE_B

    // ---- epilogue: relu(bn_red) * G + CACT, relu -> bf16 h[p][c] ----
    unsigned short* Ob = H + (size_t)bz * ((size_t)PP * CCH);
    const float* Gb = G + (size_t)bz * CCH;
#pragma unroll
    for (int j = 0; j < 4; ++j) {
        int c = n0 + (wn << 6) + (j << 4) + l15;
        float a1c = C0[c], b1c = C1[c], cac = C2[c], gc = Gb[c];
#pragma unroll
        for (int i = 0; i < 4; ++i) {
            int pr = m0 + (wm << 6) + (i << 4) + (l4v << 2);
#pragma unroll
            for (int q = 0; q < 4; ++q) {
                float xr = fmaxf(a1c * acc[i][j][q] + b1c, 0.f);
                float hv = fmaxf(gc * xr + cac, 0.f);
                Ob[(size_t)(pr + q) * CCH + c] = f2bf(hv);
            }
        }
    }
}

// ============================================================================
// GEMM2: out[b][c][p] = relu(bn_fus(wfus . h));  A = wfus_bf [c][k], B = h [p][k]
// 128x128 tile, BK=32, 4 waves, both operands gloaded depth-2 (3-buf each),
// 48KB LDS -> 3 blocks/CU.  Swizzle m2 = (row>>1)&3 on 4-unit rows.
// ============================================================================
__global__ __launch_bounds__(256, 3)
void k_gemm2(const unsigned short* __restrict__ A, const unsigned short* __restrict__ Bt,
             float* __restrict__ Out,
             const float* __restrict__ C0, const float* __restrict__ C1) {
    __shared__ __align__(16) char sm[49152];
    constexpr int NT = 16;      // K=512 / BK=32

    int r = blockIdx.x + (blockIdx.y << 5) + (blockIdx.z << 7);
    int w = ((r & 7) << 7) | (r >> 3);
    const int n0 = (w & 31) << 7;        // p
    const int m0 = ((w >> 5) & 3) << 7;  // c
    const int bz = w >> 7;

    const int t = threadIdx.x;
    const int lane = t & 63, wave = t >> 6;
    const int l15 = lane & 15, l4v = lane >> 4;
    const int wm = wave >> 1, wn = wave & 1;

    // staging: tile = 128 rows x 4 units; 512 units -> 2 gload rounds per operand
    const unsigned short* Abase = A + (size_t)m0 * 512;
    const unsigned short* Bbase = Bt + (size_t)bz * ((size_t)PP * CCH) + (size_t)n0 * 512;
    const unsigned short* pAsrc[2]; const unsigned short* pBsrc[2];
    int sdst[2];
#pragma unroll
    for (int q = 0; q < 2; ++q) {
        int du = (wave << 6) + lane + (q << 8);
        int row = du >> 2, g = du & 3;
        int m2 = (row >> 1) & 3;
        pAsrc[q] = Abase + (size_t)row * 512 + ((g ^ m2) << 3);
        pBsrc[q] = Bbase + (size_t)row * 512 + ((g ^ m2) << 3);
        sdst[q] = ((wave << 6) + (q << 8)) << 4;
    }

    int offA[4], offB[4];
#pragma unroll
    for (int i = 0; i < 4; ++i) {
        int rowA = (wm << 6) + (i << 4) + l15;
        int rowB = (wn << 6) + (i << 4) + l15;
        offA[i] = rowA * 64 + ((l4v ^ ((rowA >> 1) & 3)) << 4);
        offB[i] = rowB * 64 + ((l4v ^ ((rowB >> 1) & 3)) << 4);
    }

#define STAGE2(tt, b3_) { char* dA_ = sm + ((b3_) << 13); char* dB_ = sm + 24576 + ((b3_) << 13); \
        gload16(pAsrc[0] + (tt) * 32, dA_ + sdst[0]); \
        gload16(pAsrc[1] + (tt) * 32, dA_ + sdst[1]); \
        gload16(pBsrc[0] + (tt) * 32, dB_ + sdst[0]); \
        gload16(pBsrc[1] + (tt) * 32, dB_ + sdst[1]); }

    f32x4 acc[4][4];
#pragma unroll
    for (int i = 0; i < 4; ++i)
#pragma unroll
        for (int j = 0; j < 4; ++j) acc[i][j] = (f32x4){0.f, 0.f, 0.f, 0.f};

    // prologue: S(0), S(1); S(0) landed before barrier
    STAGE2(0, 0)
    STAGE2(1, 1)
    asm volatile("s_waitcnt vmcnt(4)" ::: "memory");
    __builtin_amdgcn_s_barrier();               // entering t=0: [S(1)=4]

    int b3 = 0;
    for (int tk = 0; tk < NT; ++tk) {
        char* aB = sm + (b3 << 13);
        char* bB = sm + 24576 + (b3 << 13);
        bf16x8 af[4], bf_[4];
#pragma unroll
        for (int i = 0; i < 4; ++i) {
            af[i]  = *(const bf16x8*)(aB + offA[i]);
            bf_[i] = *(const bf16x8*)(bB + offB[i]);
        }
        if (tk + 2 < NT) {
            int nb = b3 - 1; if (nb < 0) nb += 3;
            STAGE2(tk + 2, nb)
        }
#pragma unroll
        for (int i = 0; i < 4; ++i)
#pragma unroll
            for (int j = 0; j < 4; ++j)
                acc[i][j] = __builtin_amdgcn_mfma_f32_16x16x32_bf16(af[i], bf_[j], acc[i][j], 0, 0, 0);
        if (tk < NT - 2) {
            asm volatile("s_waitcnt vmcnt(4)" ::: "memory");   // S(tk+1) landed pre-barrier
            __builtin_amdgcn_s_barrier();
        } else if (tk == NT - 2) {
            asm volatile("s_waitcnt vmcnt(0)" ::: "memory");
            __builtin_amdgcn_s_barrier();
        }
        b3 = (b3 == 2) ? 0 : b3 + 1;
    }
#undef STAGE2

    // epilogue: fp32 out, BN_fus + ReLU; out[b][c][p]
    float* Ob = Out + (size_t)bz * ((size_t)CCH * PP);
#pragma unroll
    for (int i = 0; i < 4; ++i) {
#pragma unroll
        for (int q = 0; q < 4; ++q) {
            int orow = m0 + (wm << 6) + (i << 4) + (l4v << 2) + q;
            float a2 = C0[orow], b2 = C1[orow];
#pragma unroll
            for (int j = 0; j < 4; ++j) {
                int pc = n0 + (wn << 6) + (j << 4) + l15;
                Ob[(size_t)orow * PP + pc] = fmaxf(a2 * acc[i][j][q] + b2, 0.f);
            }
        }
    }
}

extern "C" void kernel_launch(void* const* d_in, const int* in_sizes, int n_in,
                              void* d_out, int out_size, void* d_ws, size_t ws_size,
                              hipStream_t stream) {
    const float* x      = (const float*)d_in[0];
    const float* y      = (const float*)d_in[1];
    const float* w_red  = (const float*)d_in[2];
    const float* b_red  = (const float*)d_in[3];
    const float* g_red  = (const float*)d_in[4];
    const float* be_red = (const float*)d_in[5];
    const float* m_red  = (const float*)d_in[6];
    const float* v_red  = (const float*)d_in[7];
    const float* w_gen  = (const float*)d_in[8];
    const float* b_gen  = (const float*)d_in[9];
    const float* g_gen  = (const float*)d_in[10];
    const float* be_gen = (const float*)d_in[11];
    const float* m_gen  = (const float*)d_in[12];
    const float* v_gen  = (const float*)d_in[13];
    const float* g_act  = (const float*)d_in[14];
    const float* be_act = (const float*)d_in[15];
    const float* m_act  = (const float*)d_in[16];
    const float* v_act  = (const float*)d_in[17];
    const float* w_fus  = (const float*)d_in[18];
    const float* b_fus  = (const float*)d_in[19];
    const float* g_fus  = (const float*)d_in[20];
    const float* be_fus = (const float*)d_in[21];
    const float* m_fus  = (const float*)d_in[22];
    const float* v_fus  = (const float*)d_in[23];

    // workspace layout (bytes)
    const size_t off_h    = 67108864;                   // 33554432
    const size_t off_wred = 100663296;                  // 1048576
    const size_t off_wfus = 101711872;                  // 524288
    const size_t off_pool = 102236160;                  // 16384
    const size_t off_G    = 102252544;                  // 16384
    const size_t off_cst  = 102268928;                  // 6*2048
    const size_t need     = off_cst + 6 * 2048;
    if (ws_size < need) return;

    char* ws = (char*)d_ws;
    unsigned short* h       = (unsigned short*)(ws + off_h);
    unsigned short* wred_bf = (unsigned short*)(ws + off_wred);
    unsigned short* wfus_bf = (unsigned short*)(ws + off_wfus);
    float* ypool = (float*)(ws + off_pool);
    float* G     = (float*)(ws + off_G);
    float* A1    = (float*)(ws + off_cst);
    float* B1    = A1 + 512;
    float* CACT  = B1 + 512;
    float* A2    = CACT + 512;
    float* B2    = A2 + 512;

    k_pre<<<4864, 256, 0, stream>>>(y, w_red, w_fus, ypool, wred_bf, wfus_bf);
    k_gf2<<<18, 256, 0, stream>>>(w_gen, b_gen, g_gen, be_gen, m_gen, v_gen, ypool,
                                  g_red, be_red, m_red, v_red, b_red,
                                  g_act, be_act, m_act, v_act,
                                  g_fus, be_fus, m_fus, v_fus, b_fus,
                                  G, A1, B1, CACT, A2, B2);

    dim3 g1(4, 32, 8);   // n=512/128, m=4096/128, batch
    k_gemm1<<<g1, 256, 0, stream>>>(x, wred_bf, h, A1, B1, CACT, G);
    dim3 g2(32, 4, 8);   // n=4096/128, m=512/128, batch
    k_gemm2<<<g2, 256, 0, stream>>>(wfus_bf, h, (float*)d_out, A2, B2);
}

// Round 7
// 129.298 us; speedup vs baseline: 1.1880x; 1.0023x over previous
//
#include <hip/hip_runtime.h>
#include <hip/hip_bf16.h>
#include <stdint.h>

#define EPSBN 1e-5f

typedef float f32x4 __attribute__((ext_vector_type(4)));
typedef __bf16 bf16x8 __attribute__((ext_vector_type(8)));

#define BB 8
#define XCH 1024
#define YCH 512
#define CCH 512
#define PP  4096   // H*W = 64*64

__device__ __forceinline__ unsigned short f2bf(float f) {
    union { float f; uint32_t u; } v; v.f = f;
    uint32_t r = v.u + 0x7fffu + ((v.u >> 16) & 1u);   // RNE
    return (unsigned short)(r >> 16);
}

__device__ __forceinline__ uint32_t pkbf(float lo, float hi) {
    uint32_t r;
    asm volatile("v_cvt_pk_bf16_f32 %0, %1, %2" : "=v"(r) : "v"(lo), "v"(hi));
    return r;
}

__device__ __forceinline__ void gload16(const void* g, void* l) {
    __builtin_amdgcn_global_load_lds(
        (__attribute__((address_space(1))) void*)(g),
        (__attribute__((address_space(3))) void*)(l),
        16, 0, 0);
}

// ---------- fused: y_pool (blocks 0..4095) + weight cvt (blocks 4096..4863) ----------
__global__ __launch_bounds__(256)
void k_pre(const float* __restrict__ y, const float* __restrict__ wred, const float* __restrict__ wfus,
           float* __restrict__ ypool, unsigned short* __restrict__ wred_bf, unsigned short* __restrict__ wfus_bf) {
    int bx = blockIdx.x, t = threadIdx.x;
    if (bx < 4096) {
        const float4* base = (const float4*)(y + (size_t)bx * PP);
        float s = 0.f;
#pragma unroll
        for (int it = 0; it < 4; ++it) {
            float4 v = base[t + it * 256];
            s += v.x + v.y + v.z + v.w;
        }
#pragma unroll
        for (int off = 32; off > 0; off >>= 1) s += __shfl_down(s, off);
        __shared__ float wsum[4];
        if ((t & 63) == 0) wsum[t >> 6] = s;
        __syncthreads();
        if (t == 0) ypool[bx] = (wsum[0] + wsum[1] + wsum[2] + wsum[3]) * (1.f / 4096.f);
    } else {
        int idx = (bx - 4096) * 256 + t;                   // < 196608
        const int n1 = CCH * XCH / 4;                      // 131072
        float4 v; unsigned short* dst;
        if (idx < n1) { v = ((const float4*)wred)[idx]; dst = wred_bf + (size_t)idx * 4; }
        else { int j = idx - n1; v = ((const float4*)wfus)[j]; dst = wfus_bf + (size_t)j * 4; }
        *(uint2*)dst = make_uint2(((uint32_t)f2bf(v.x)) | ((uint32_t)f2bf(v.y) << 16),
                                  ((uint32_t)f2bf(v.z)) | ((uint32_t)f2bf(v.w) << 16));
    }
}

// ---------- fused: G (blocks 0..15) + BN-const folding (blocks 16..17) ----------
__global__ __launch_bounds__(256)
void k_gf2(const float* __restrict__ wgen, const float* __restrict__ bgen,
           const float* __restrict__ ggen, const float* __restrict__ begen,
           const float* __restrict__ mgen, const float* __restrict__ vgen,
           const float* __restrict__ ypool,
           const float* g_red, const float* be_red, const float* m_red, const float* v_red, const float* b_red,
           const float* g_act, const float* be_act, const float* m_act, const float* v_act,
           const float* g_fus, const float* be_fus, const float* m_fus, const float* v_fus, const float* b_fus,
           float* __restrict__ G, float* A1, float* B1, float* CACT, float* A2, float* B2) {
    int bx = blockIdx.x, t = threadIdx.x;
    if (bx < 16) {
        int idx = bx * 256 + t;
        int b = idx >> 9, c = idx & 511;
        const float4* wr = (const float4*)(wgen + (size_t)c * YCH);
        const float4* yp = (const float4*)(ypool + b * YCH);
        float dot = 0.f;
        for (int k = 0; k < YCH / 4; ++k) {
            float4 w = wr[k], v = yp[k];
            dot += w.x * v.x + w.y * v.y + w.z * v.z + w.w * v.w;
        }
        float ag = ggen[c] * rsqrtf(vgen[c] + EPSBN);
        float gf = fmaxf(ag * (dot + bgen[c] - mgen[c]) + begen[c], 0.f);
        float aa = g_act[c] * rsqrtf(v_act[c] + EPSBN);
        G[idx] = aa * gf;
    } else {
        int c = (bx - 16) * 256 + t;
        if (c >= CCH) return;
        float a1 = g_red[c] * rsqrtf(v_red[c] + EPSBN);
        A1[c] = a1;
        B1[c] = a1 * (b_red[c] - m_red[c]) + be_red[c];
        float aa = g_act[c] * rsqrtf(v_act[c] + EPSBN);
        CACT[c] = be_act[c] - aa * m_act[c];
        float a2 = g_fus[c] * rsqrtf(v_fus[c] + EPSBN);
        A2[c] = a2;
        B2[c] = a2 * (b_fus[c] - m_fus[c]) + be_fus[c];
    }
}

// ============================================================================
// GEMM1: h[b][p][c] = epi( sum_k x[b][k][p] * wred[c][k] )
// 128x128 tile, BK=64, 4 waves, depth-2 pipeline, 1 raw s_barrier/tile.
// LDS: Abuf 2x16KB @0, Bbuf 3x16KB @32768 (80KB -> 2 blocks/CU).
// Swizzle: unit(row,kg) stored at kg' = kg ^ ((row ^ (row>>2)) & 7).
//   frag reads 2-way (free); transpose ds_write_b128 2-way (free).
// Steady interval t: reads | vmcnt(4) AWRITE(t+1) | ALOAD(t+2) STAGE_B(t+2)
//   | 32 MFMA | vmcnt(12) lgkmcnt(0) | s_barrier.  (waits only touch loads
//   issued >= 1 interval earlier; B(t+1) retired BEFORE the barrier that
//   gates its cross-wave consumption.)
// ============================================================================
__global__ __launch_bounds__(256, 2)
void k_gemm1(const float* __restrict__ X, const unsigned short* __restrict__ Bt,
             unsigned short* __restrict__ H,
             const float* __restrict__ C0, const float* __restrict__ C1,
             const float* __restrict__ C2, const float* __restrict__ G) {
    __shared__ __align__(16) char sm[81920];
    constexpr int NT = 16;      // K=1024 / BK=64

    int r = blockIdx.x + (blockIdx.y << 2) + (blockIdx.z << 7);
    int w = ((r & 7) << 7) | (r >> 3);          // batch-chunk per XCD
    const int n0 = (w & 3) << 7;
    const int m0 = ((w >> 2) & 31) << 7;
    const int bz = w >> 7;

    const int t = threadIdx.x;
    const int lane = t & 63, wave = t >> 6;
    const int l15 = lane & 15, l4v = lane >> 4;
    const int wm = wave >> 1, wn = wave & 1;

    // ---- A-path mapping: pq = p-quad (lane&31), ko = k-octet (0..7)
    const int pq = lane & 31;
    const int ko = (wave << 1) | (lane >> 5);
    const float* xb = X + (size_t)bz * ((size_t)XCH * PP) + m0 + (pq << 2);
    int awb[4];
#pragma unroll
    for (int rr = 0; rr < 4; ++rr) {
        int row = (pq << 2) + rr;
        int mm = (row ^ (row >> 2)) & 7;
        awb[rr] = row * 128 + ((ko ^ mm) << 4);
    }

    // ---- B staging: 4 gload16/tile; dest linear (wave base), source pre-swizzled
    const unsigned short* Bbase = Bt + (size_t)n0 * 1024;
    const unsigned short* pBsrc[4];
    int bdst[4];
#pragma unroll
    for (int q = 0; q < 4; ++q) {
        int du = (wave << 6) + lane + (q << 8);
        int row = du >> 3, g = du & 7;
        int mm = (row ^ (row >> 2)) & 7;
        pBsrc[q] = Bbase + (size_t)row * 1024 + ((g ^ mm) << 3);
        bdst[q] = ((wave << 6) + (q << 8)) << 4;   // wave-uniform; HW adds lane*16
    }

    // ---- frag read byte offsets (loop-invariant)
    int offA[4][2], offB[4][2];
#pragma unroll
    for (int i = 0; i < 4; ++i) {
        int rowA = (wm << 6) + (i << 4) + l15;
        int mA = (rowA ^ (rowA >> 2)) & 7;
        int rowB = (wn << 6) + (i << 4) + l15;
        int mB = (rowB ^ (rowB >> 2)) & 7;
#pragma unroll
        for (int k2 = 0; k2 < 2; ++k2) {
            offA[i][k2] = rowA * 128 + ((((k2 << 2) | l4v) ^ mA) << 4);
            offB[i][k2] = rowB * 128 + ((((k2 << 2) | l4v) ^ mB) << 4);
        }
    }

    float4 R0, R1, R2, R3, R4, R5, R6, R7;
#define ALOAD(tt) { const float* p_ = xb + (size_t)((tt) * 64 + (ko << 3)) * PP; \
        R0 = *(const float4*)p_;              R1 = *(const float4*)(p_ + PP); \
        R2 = *(const float4*)(p_ + 2 * PP);   R3 = *(const float4*)(p_ + 3 * PP); \
        R4 = *(const float4*)(p_ + 4 * PP);   R5 = *(const float4*)(p_ + 5 * PP); \
        R6 = *(const float4*)(p_ + 6 * PP);   R7 = *(const float4*)(p_ + 7 * PP); }

#define AWRITE(buf2) { char* ab_ = sm + ((buf2) << 14); \
        _Pragma("unroll") \
        for (int rr = 0; rr < 4; ++rr) { \
            uint4 v_; \
            v_.x = pkbf(((const float*)&R0)[rr], ((const float*)&R1)[rr]); \
            v_.y = pkbf(((const float*)&R2)[rr], ((const float*)&R3)[rr]); \
            v_.z = pkbf(((const float*)&R4)[rr], ((const float*)&R5)[rr]); \
            v_.w = pkbf(((const float*)&R6)[rr], ((const float*)&R7)[rr]); \
            *(uint4*)(ab_ + awb[rr]) = v_; } }

#define STAGE_B(tt, b3_) { char* d_ = sm + 32768 + ((b3_) << 14); \
        gload16(pBsrc[0] + (tt) * 64, d_ + bdst[0]); \
        gload16(pBsrc[1] + (tt) * 64, d_ + bdst[1]); \
        gload16(pBsrc[2] + (tt) * 64, d_ + bdst[2]); \
        gload16(pBsrc[3] + (tt) * 64, d_ + bdst[3]); }

    f32x4 acc[4][4];
#pragma unroll
    for (int i = 0; i < 4; ++i)
#pragma unroll
        for (int j = 0; j < 4; ++j) acc[i][j] = (f32x4){0.f, 0.f, 0.f, 0.f};

    // ---- prologue ----
    ALOAD(0)
    asm volatile("" ::: "memory");
    STAGE_B(0, 0)
    asm volatile("s_waitcnt vmcnt(4)" ::: "memory");     // A(0) in regs (B(0) still flying)
    AWRITE(0)                                            // -> Abuf[0]
    ALOAD(1)
    asm volatile("" ::: "memory");
    STAGE_B(1, 1)
    asm volatile("s_waitcnt vmcnt(12) lgkmcnt(0)" ::: "memory");  // B(0) landed, AWRITE visible
    __builtin_amdgcn_s_barrier();                        // entering t=0: [A(1)=8, B(1)=4]

    int b3 = 0;
    for (int tk = 0; tk < NT; ++tk) {
        char* aB = sm + ((tk & 1) << 14);
        char* bB = sm + 32768 + (b3 << 14);
        bf16x8 a0[4], b0[4], a1[4], b1[4];
#pragma unroll
        for (int i = 0; i < 4; ++i) {
            a0[i] = *(const bf16x8*)(aB + offA[i][0]);
            b0[i] = *(const bf16x8*)(bB + offB[i][0]);
            a1[i] = *(const bf16x8*)(aB + offA[i][1]);
            b1[i] = *(const bf16x8*)(bB + offB[i][1]);
        }
        if (tk + 1 < NT) {
            asm volatile("s_waitcnt vmcnt(4)" ::: "memory");   // own A(tk+1) regs ready
            AWRITE((tk + 1) & 1)
        }
        if (tk + 2 < NT) {
            int nb = b3 - 1; if (nb < 0) nb += 3;              // (b3+2)%3
            ALOAD(tk + 2)
            asm volatile("" ::: "memory");                     // pin A-before-B issue order
            STAGE_B(tk + 2, nb)
        }
#pragma unroll
        for (int i = 0; i < 4; ++i)
#pragma unroll
            for (int j = 0; j < 4; ++j)
                acc[i][j] = __builtin_amdgcn_mfma_f32_16x16x32_bf16(a0[i], b0[j], acc[i][j], 0, 0, 0);
#pragma unroll
        for (int i = 0; i < 4; ++i)
#pragma unroll
            for (int j = 0; j < 4; ++j)
                acc[i][j] = __builtin_amdgcn_mfma_f32_16x16x32_bf16(a1[i], b1[j], acc[i][j], 0, 0, 0);
        if (tk < NT - 2) {
            asm volatile("s_waitcnt vmcnt(12) lgkmcnt(0)" ::: "memory");  // B(tk+1) landed pre-barrier
            __builtin_amdgcn_s_barrier();
        } else if (tk == NT - 2) {
            asm volatile("s_waitcnt vmcnt(0) lgkmcnt(0)" ::: "memory");
            __builtin_amdgcn_s_barrier();
        }
        b3 = (b3 == 2) ? 0 : b3 + 1;
    }
#undef ALOAD
#undef AWRITE
#undef STAGE_B

    // ---- epilogue: relu(bn_red) * G + CACT, relu -> bf16 h[p][c] ----
    unsigned short* Ob = H + (size_t)bz * ((size_t)PP * CCH);
    const float* Gb = G + (size_t)bz * CCH;
#pragma unroll
    for (int j = 0; j < 4; ++j) {
        int c = n0 + (wn << 6) + (j << 4) + l15;
        float a1c = C0[c], b1c = C1[c], cac = C2[c], gc = Gb[c];
#pragma unroll
        for (int i = 0; i < 4; ++i) {
            int pr = m0 + (wm << 6) + (i << 4) + (l4v << 2);
#pragma unroll
            for (int q = 0; q < 4; ++q) {
                float xr = fmaxf(a1c * acc[i][j][q] + b1c, 0.f);
                float hv = fmaxf(gc * xr + cac, 0.f);
                Ob[(size_t)(pr + q) * CCH + c] = f2bf(hv);
            }
        }
    }
}

// ============================================================================
// GEMM2: out[b][c][p] = relu(bn_fus(wfus . h));  A = wfus_bf [c][k], B = h [p][k]
// 128x128 tile, BK=32, 4 waves, both operands gloaded depth-2 (3-buf each),
// 48KB LDS -> 3 blocks/CU.  Swizzle m2 = (row>>1)&3 on 4-unit rows.
// ============================================================================
__global__ __launch_bounds__(256, 3)
void k_gemm2(const unsigned short* __restrict__ A, const unsigned short* __restrict__ Bt,
             float* __restrict__ Out,
             const float* __restrict__ C0, const float* __restrict__ C1) {
    __shared__ __align__(16) char sm[49152];
    constexpr int NT = 16;      // K=512 / BK=32

    int r = blockIdx.x + (blockIdx.y << 5) + (blockIdx.z << 7);
    int w = ((r & 7) << 7) | (r >> 3);
    const int n0 = (w & 31) << 7;        // p
    const int m0 = ((w >> 5) & 3) << 7;  // c
    const int bz = w >> 7;

    const int t = threadIdx.x;
    const int lane = t & 63, wave = t >> 6;
    const int l15 = lane & 15, l4v = lane >> 4;
    const int wm = wave >> 1, wn = wave & 1;

    // staging: tile = 128 rows x 4 units; 512 units -> 2 gload rounds per operand
    const unsigned short* Abase = A + (size_t)m0 * 512;
    const unsigned short* Bbase = Bt + (size_t)bz * ((size_t)PP * CCH) + (size_t)n0 * 512;
    const unsigned short* pAsrc[2]; const unsigned short* pBsrc[2];
    int sdst[2];
#pragma unroll
    for (int q = 0; q < 2; ++q) {
        int du = (wave << 6) + lane + (q << 8);
        int row = du >> 2, g = du & 3;
        int m2 = (row >> 1) & 3;
        pAsrc[q] = Abase + (size_t)row * 512 + ((g ^ m2) << 3);
        pBsrc[q] = Bbase + (size_t)row * 512 + ((g ^ m2) << 3);
        sdst[q] = ((wave << 6) + (q << 8)) << 4;
    }

    int offA[4], offB[4];
#pragma unroll
    for (int i = 0; i < 4; ++i) {
        int rowA = (wm << 6) + (i << 4) + l15;
        int rowB = (wn << 6) + (i << 4) + l15;
        offA[i] = rowA * 64 + ((l4v ^ ((rowA >> 1) & 3)) << 4);
        offB[i] = rowB * 64 + ((l4v ^ ((rowB >> 1) & 3)) << 4);
    }

#define STAGE2(tt, b3_) { char* dA_ = sm + ((b3_) << 13); char* dB_ = sm + 24576 + ((b3_) << 13); \
        gload16(pAsrc[0] + (tt) * 32, dA_ + sdst[0]); \
        gload16(pAsrc[1] + (tt) * 32, dA_ + sdst[1]); \
        gload16(pBsrc[0] + (tt) * 32, dB_ + sdst[0]); \
        gload16(pBsrc[1] + (tt) * 32, dB_ + sdst[1]); }

    f32x4 acc[4][4];
#pragma unroll
    for (int i = 0; i < 4; ++i)
#pragma unroll
        for (int j = 0; j < 4; ++j) acc[i][j] = (f32x4){0.f, 0.f, 0.f, 0.f};

    // prologue: S(0), S(1); S(0) landed before barrier
    STAGE2(0, 0)
    STAGE2(1, 1)
    asm volatile("s_waitcnt vmcnt(4)" ::: "memory");
    __builtin_amdgcn_s_barrier();               // entering t=0: [S(1)=4]

    int b3 = 0;
    for (int tk = 0; tk < NT; ++tk) {
        char* aB = sm + (b3 << 13);
        char* bB = sm + 24576 + (b3 << 13);
        bf16x8 af[4], bf_[4];
#pragma unroll
        for (int i = 0; i < 4; ++i) {
            af[i]  = *(const bf16x8*)(aB + offA[i]);
            bf_[i] = *(const bf16x8*)(bB + offB[i]);
        }
        if (tk + 2 < NT) {
            int nb = b3 - 1; if (nb < 0) nb += 3;
            STAGE2(tk + 2, nb)
        }
#pragma unroll
        for (int i = 0; i < 4; ++i)
#pragma unroll
            for (int j = 0; j < 4; ++j)
                acc[i][j] = __builtin_amdgcn_mfma_f32_16x16x32_bf16(af[i], bf_[j], acc[i][j], 0, 0, 0);
        if (tk < NT - 2) {
            asm volatile("s_waitcnt vmcnt(4)" ::: "memory");   // S(tk+1) landed pre-barrier
            __builtin_amdgcn_s_barrier();
        } else if (tk == NT - 2) {
            asm volatile("s_waitcnt vmcnt(0)" ::: "memory");
            __builtin_amdgcn_s_barrier();
        }
        b3 = (b3 == 2) ? 0 : b3 + 1;
    }
#undef STAGE2

    // epilogue: fp32 out, BN_fus + ReLU; out[b][c][p]
    float* Ob = Out + (size_t)bz * ((size_t)CCH * PP);
#pragma unroll
    for (int i = 0; i < 4; ++i) {
#pragma unroll
        for (int q = 0; q < 4; ++q) {
            int orow = m0 + (wm << 6) + (i << 4) + (l4v << 2) + q;
            float a2 = C0[orow], b2 = C1[orow];
#pragma unroll
            for (int j = 0; j < 4; ++j) {
                int pc = n0 + (wn << 6) + (j << 4) + l15;
                Ob[(size_t)orow * PP + pc] = fmaxf(a2 * acc[i][j][q] + b2, 0.f);
            }
        }
    }
}

extern "C" void kernel_launch(void* const* d_in, const int* in_sizes, int n_in,
                              void* d_out, int out_size, void* d_ws, size_t ws_size,
                              hipStream_t stream) {
    const float* x      = (const float*)d_in[0];
    const float* y      = (const float*)d_in[1];
    const float* w_red  = (const float*)d_in[2];
    const float* b_red  = (const float*)d_in[3];
    const float* g_red  = (const float*)d_in[4];
    const float* be_red = (const float*)d_in[5];
    const float* m_red  = (const float*)d_in[6];
    const float* v_red  = (const float*)d_in[7];
    const float* w_gen  = (const float*)d_in[8];
    const float* b_gen  = (const float*)d_in[9];
    const float* g_gen  = (const float*)d_in[10];
    const float* be_gen = (const float*)d_in[11];
    const float* m_gen  = (const float*)d_in[12];
    const float* v_gen  = (const float*)d_in[13];
    const float* g_act  = (const float*)d_in[14];
    const float* be_act = (const float*)d_in[15];
    const float* m_act  = (const float*)d_in[16];
    const float* v_act  = (const float*)d_in[17];
    const float* w_fus  = (const float*)d_in[18];
    const float* b_fus  = (const float*)d_in[19];
    const float* g_fus  = (const float*)d_in[20];
    const float* be_fus = (const float*)d_in[21];
    const float* m_fus  = (const float*)d_in[22];
    const float* v_fus  = (const float*)d_in[23];

    // workspace layout (bytes)
    const size_t off_h    = 67108864;                   // 33554432
    const size_t off_wred = 100663296;                  // 1048576
    const size_t off_wfus = 101711872;                  // 524288
    const size_t off_pool = 102236160;                  // 16384
    const size_t off_G    = 102252544;                  // 16384
    const size_t off_cst  = 102268928;                  // 6*2048
    const size_t need     = off_cst + 6 * 2048;
    if (ws_size < need) return;

    char* ws = (char*)d_ws;
    unsigned short* h       = (unsigned short*)(ws + off_h);
    unsigned short* wred_bf = (unsigned short*)(ws + off_wred);
    unsigned short* wfus_bf = (unsigned short*)(ws + off_wfus);
    float* ypool = (float*)(ws + off_pool);
    float* G     = (float*)(ws + off_G);
    float* A1    = (float*)(ws + off_cst);
    float* B1    = A1 + 512;
    float* CACT  = B1 + 512;
    float* A2    = CACT + 512;
    float* B2    = A2 + 512;

    k_pre<<<4864, 256, 0, stream>>>(y, w_red, w_fus, ypool, wred_bf, wfus_bf);
    k_gf2<<<18, 256, 0, stream>>>(w_gen, b_gen, g_gen, be_gen, m_gen, v_gen, ypool,
                                  g_red, be_red, m_red, v_red, b_red,
                                  g_act, be_act, m_act, v_act,
                                  g_fus, be_fus, m_fus, v_fus, b_fus,
                                  G, A1, B1, CACT, A2, B2);

    dim3 g1(4, 32, 8);   // n=512/128, m=4096/128, batch
    k_gemm1<<<g1, 256, 0, stream>>>(x, wred_bf, h, A1, B1, CACT, G);
    dim3 g2(32, 4, 8);   // n=4096/128, m=512/128, batch
    k_gemm2<<<g2, 256, 0, stream>>>(wfus_bf, h, (float*)d_out, A2, B2);
}